// Round 14
// baseline (148.989 us; speedup 1.0000x reference)
//
#include <hip/hip_runtime.h>

#define N_NODES 100000
#define N_EDGES 6400000

#define HSCALE 4096.0f           // 2^12 fixed point for h
#define HCLAMP 63.0f             // |hfix| <= 258048 < 2^18

// ---- Partition geometry -----------------------------------------------------
#define QBIN       4096          // nodes per bin (pow2 -> shift/mask)
#define QBIN_SHIFT 12
#define NQBINS     25            // 25*4096 = 102400 >= 100000
#define PBLOCKS    200           // 8000 quads per block, exact
#define PTHREADS   1024
#define LCAP       1536          // per-(bin,block) segment: mean 1280, +7.2 sigma
#define NQBLK      20            // accumulate blocks per bin -> grid 500
#define QTHREADS   1024

typedef int int4v __attribute__((ext_vector_type(4)));
typedef unsigned uint4v __attribute__((ext_vector_type(4)));

// ---------------------------------------------------------------------------
// Pass P (fused MLP + partition).  4-quad ILP; rec = (src<<12)|(dst&4095);
// per-bin LDS buckets -> fixed global segments (no global atomics).  Also
// zeroes the per-bin arrival counters used by the fused accumulate.
// ---------------------------------------------------------------------------
__global__ __launch_bounds__(PTHREADS)
void partition_kernel(const float* __restrict__ x,
                      const float* __restrict__ W1,
                      const float* __restrict__ b1,
                      const float* __restrict__ W2,
                      const float* __restrict__ b2,
                      const int* __restrict__ src,
                      const int* __restrict__ dst,
                      int* __restrict__ hfix,
                      unsigned* __restrict__ recs,     // [NQBINS*PBLOCKS*LCAP]
                      unsigned* __restrict__ counts,   // [NQBINS*PBLOCKS]
                      unsigned* __restrict__ done) {   // [NQBINS]
    extern __shared__ unsigned sbuf[];                 // NQBINS*LCAP u32 (150KB)
    __shared__ unsigned scnt[NQBINS];
    const int tid = threadIdx.x;

    if (blockIdx.x == 0 && tid < NQBINS) done[tid] = 0u;  // visible at kernel end

    // --- fused MLP: one node per thread across the grid ---
    int node = blockIdx.x * PTHREADS + tid;
    if (node < N_NODES) {
        float xv = x[node];
        float acc = b2[0];
#pragma unroll
        for (int k = 0; k < 16; ++k) {
            float t = fmaxf(W1[k] * xv + b1[k], 0.0f);
            acc = fmaf(W2[k], t, acc);
        }
        acc = fminf(fmaxf(acc, -HCLAMP), HCLAMP);
        hfix[node] = __float2int_rn(acc * HSCALE);
    }

    if (tid < NQBINS) scnt[tid] = 0u;
    __syncthreads();

    const int quads = (N_EDGES / 4) / PBLOCKS;          // 8000 exact
    const int4v* __restrict__ s4 = (const int4v*)src + (size_t)blockIdx.x * quads;
    const int4v* __restrict__ d4 = (const int4v*)dst + (size_t)blockIdx.x * quads;

#define PROC(D, S)                                                            \
    {                                                                         \
        int b0 = (D).x >> QBIN_SHIFT, b1_ = (D).y >> QBIN_SHIFT;              \
        int b2_ = (D).z >> QBIN_SHIFT, b3 = (D).w >> QBIN_SHIFT;              \
        unsigned r0 = ((unsigned)(S).x << 12) | (unsigned)((D).x & (QBIN-1)); \
        unsigned r1 = ((unsigned)(S).y << 12) | (unsigned)((D).y & (QBIN-1)); \
        unsigned r2 = ((unsigned)(S).z << 12) | (unsigned)((D).z & (QBIN-1)); \
        unsigned r3 = ((unsigned)(S).w << 12) | (unsigned)((D).w & (QBIN-1)); \
        unsigned sl0 = atomicAdd(&scnt[b0], 1u);                              \
        unsigned sl1 = atomicAdd(&scnt[b1_], 1u);                             \
        unsigned sl2 = atomicAdd(&scnt[b2_], 1u);                             \
        unsigned sl3 = atomicAdd(&scnt[b3], 1u);                              \
        if (sl0 < (unsigned)LCAP) sbuf[b0 * LCAP + sl0] = r0;                 \
        if (sl1 < (unsigned)LCAP) sbuf[b1_ * LCAP + sl1] = r1;                \
        if (sl2 < (unsigned)LCAP) sbuf[b2_ * LCAP + sl2] = r2;                \
        if (sl3 < (unsigned)LCAP) sbuf[b3 * LCAP + sl3] = r3;                 \
    }

    for (int i = tid; i < quads; i += 4 * PTHREADS) {
        const int i1 = i + PTHREADS, i2 = i + 2 * PTHREADS, i3 = i + 3 * PTHREADS;
        const bool h1 = i1 < quads, h2 = i2 < quads, h3 = i3 < quads;
        int4v d0 = d4[i];
        int4v s0 = s4[i];
        int4v d1, s1, d2, s2, d3, s3;
        if (h1) { d1 = d4[i1]; s1 = s4[i1]; }
        if (h2) { d2 = d4[i2]; s2 = s4[i2]; }
        if (h3) { d3 = d4[i3]; s3 = s4[i3]; }
        PROC(d0, s0);
        if (h1) PROC(d1, s1);
        if (h2) PROC(d2, s2);
        if (h3) PROC(d3, s3);
    }
#undef PROC
    __syncthreads();

    // Publish counts; flush buckets to fixed segments with uint4 stores.
    if (tid < NQBINS)
        counts[tid * PBLOCKS + blockIdx.x] = min(scnt[tid], (unsigned)LCAP);
    for (int b = 0; b < NQBINS; ++b) {
        const unsigned m = min(scnt[b], (unsigned)LCAP);
        const unsigned q = (m + 3u) >> 2;               // <= 384
        uint4v* __restrict__ segq =
            (uint4v*)(recs + ((size_t)b * PBLOCKS + blockIdx.x) * LCAP);
        const uint4v* __restrict__ sq = (const uint4v*)(sbuf + b * LCAP);
        for (unsigned t = tid; t < q; t += PTHREADS) segq[t] = sq[t];
    }
}

// ---------------------------------------------------------------------------
// Pass Q (accumulate + fused finalize).  4 thread-groups of 256 own strided
// segments; uint4 record loads -> 4 gather chains -> 4 guarded LDS atomics.
// After writing partials, the LAST arriving block per bin (device-scope
// arrival counter + threadfence, standard decoupled pattern) reduces the
// bin's NQBLK partials and writes the float2 output -> no finalize dispatch.
// ---------------------------------------------------------------------------
__global__ __launch_bounds__(QTHREADS)
void accumulate_kernel(const unsigned* __restrict__ recs,
                       const unsigned* __restrict__ counts,
                       const int* __restrict__ hfix,
                       unsigned* __restrict__ partials,
                       unsigned* __restrict__ done,     // [NQBINS], zeroed
                       const float* __restrict__ Ws,
                       float* __restrict__ out) {
    __shared__ unsigned acc[QBIN];   // 16 KB
    __shared__ unsigned s_old;
    const int b = blockIdx.x / NQBLK;
    const int j = blockIdx.x % NQBLK;
    const int tid = threadIdx.x;
    const int grp = tid >> 8;        // 0..3
    const int slot = tid & 255;
    for (int k = tid; k < QBIN; k += QTHREADS) acc[k] = 0u;
    __syncthreads();

    const unsigned* __restrict__ cnts = counts + (size_t)b * PBLOCKS;
    const unsigned* __restrict__ bbase = recs + (size_t)b * PBLOCKS * LCAP;

    // Segments for this block: s = j + k*NQBLK, k = 0..PBLOCKS/NQBLK-1 (=10).
    for (int k = grp; k * NQBLK + j < PBLOCKS; k += 4) {
        const int s = j + k * NQBLK;
        const unsigned m = cnts[s];
        const unsigned q = (m + 3u) >> 2;               // uint4 count <= 384
        const uint4v* __restrict__ seg4 =
            (const uint4v*)(bbase + (size_t)s * LCAP);
        for (unsigned t = slot; t < q; t += 256) {
            uint4v v = seg4[t];
            const unsigned e0 = t * 4u;
            const bool g0 = e0 < m, g1 = e0 + 1 < m, g2 = e0 + 2 < m,
                       g3 = e0 + 3 < m;
            unsigned r0 = g0 ? v.x : 0u;
            unsigned r1 = g1 ? v.y : 0u;
            unsigned r2 = g2 ? v.z : 0u;
            unsigned r3 = g3 ? v.w : 0u;
            int f0 = hfix[r0 >> 12];
            int f1 = hfix[r1 >> 12];
            int f2 = hfix[r2 >> 12];
            int f3 = hfix[r3 >> 12];
            if (g0) atomicAdd(&acc[r0 & (QBIN - 1)], (((unsigned)f0) << 8) + 1u);
            if (g1) atomicAdd(&acc[r1 & (QBIN - 1)], (((unsigned)f1) << 8) + 1u);
            if (g2) atomicAdd(&acc[r2 & (QBIN - 1)], (((unsigned)f2) << 8) + 1u);
            if (g3) atomicAdd(&acc[r3 & (QBIN - 1)], (((unsigned)f3) << 8) + 1u);
        }
    }
    __syncthreads();

    unsigned* __restrict__ outp = partials + (size_t)blockIdx.x * QBIN;
    for (int k = tid; k < QBIN; k += QTHREADS) outp[k] = acc[k];
    __syncthreads();

    // Arrival: release our partials, bump the bin counter.
    if (tid == 0) {
        __threadfence();
        s_old = atomicAdd(&done[b], 1u);
    }
    __syncthreads();
    if (s_old != (unsigned)(NQBLK - 1)) return;

    // Last block for this bin: acquire, reduce NQBLK partials, write output.
    __threadfence();
    const float w0 = Ws[0], w1 = Ws[1];
    const unsigned* __restrict__ pbase =
        partials + (size_t)(b * NQBLK) * QBIN;
    for (int local = tid; local < QBIN; local += QTHREADS) {
        const int node = (b << QBIN_SHIFT) + local;
        if (node >= N_NODES) continue;
        int cnt = 0, sum = 0;
#pragma unroll
        for (int jj = 0; jj < NQBLK; ++jj) {
            unsigned p = pbase[(size_t)jj * QBIN + local];
            cnt += (int)(p & 0xFFu);
            sum += ((int)p) >> 8;
        }
        float mean = ((float)sum * (1.0f / HSCALE)) / (float)max(cnt, 1);
        float2 o;
        o.x = mean * w0;
        o.y = mean * w1;
        ((float2*)out)[node] = o;
    }
}

// ===========================================================================
// Fallback path kernels (small workspace): standalone MLP + LDS-binned
// 3-pass scatter (R5) + packed u64 global atomics (R2).
// ===========================================================================
__global__ void mlp_kernel(const float* __restrict__ x,
                           const float* __restrict__ W1,
                           const float* __restrict__ b1,
                           const float* __restrict__ W2,
                           const float* __restrict__ b2,
                           int* __restrict__ hfix, int n) {
    int i = blockIdx.x * blockDim.x + threadIdx.x;
    if (i >= n) return;
    float xv = x[i];
    float acc = b2[0];
#pragma unroll
    for (int k = 0; k < 16; ++k) {
        float t = fmaxf(W1[k] * xv + b1[k], 0.0f);
        acc = fmaf(W2[k], t, acc);
    }
    acc = fminf(fmaxf(acc, -HCLAMP), HCLAMP);
    hfix[i] = __float2int_rn(acc * HSCALE);
}

template <int TBIN, int TNBINS>
__global__ __launch_bounds__(1024)
void scatter_binned(const int* __restrict__ src,
                    const int* __restrict__ dst,
                    const int* __restrict__ hfix,
                    unsigned* __restrict__ partials,
                    int n4_per_slice) {
    extern __shared__ unsigned acc[];
    const int bin   = blockIdx.x % TNBINS;
    const int slice = blockIdx.x / TNBINS;
    const int tid = threadIdx.x;
    for (int j = tid; j < TBIN; j += 1024) acc[j] = 0u;
    __syncthreads();
    const int bin_lo = bin * TBIN;
    const int4* __restrict__ s4 = (const int4*)src + (size_t)slice * n4_per_slice;
    const int4* __restrict__ d4 = (const int4*)dst + (size_t)slice * n4_per_slice;
#define PROC(dd, ss)                                                          \
    {                                                                         \
        unsigned r;                                                           \
        r = (unsigned)((dd).x - bin_lo);                                      \
        if (r < (unsigned)TBIN)                                               \
            atomicAdd(&acc[r], (((unsigned)hfix[(ss).x]) << 8) + 1u);         \
        r = (unsigned)((dd).y - bin_lo);                                      \
        if (r < (unsigned)TBIN)                                               \
            atomicAdd(&acc[r], (((unsigned)hfix[(ss).y]) << 8) + 1u);         \
        r = (unsigned)((dd).z - bin_lo);                                      \
        if (r < (unsigned)TBIN)                                               \
            atomicAdd(&acc[r], (((unsigned)hfix[(ss).z]) << 8) + 1u);         \
        r = (unsigned)((dd).w - bin_lo);                                      \
        if (r < (unsigned)TBIN)                                               \
            atomicAdd(&acc[r], (((unsigned)hfix[(ss).w]) << 8) + 1u);         \
    }
    for (int i = tid; i < n4_per_slice; i += 2048) {
        int4 d0 = d4[i];
        int4 s0 = s4[i];
        const int i1 = i + 1024;
        int4 d1, s1;
        const bool have1 = i1 < n4_per_slice;
        if (have1) { d1 = d4[i1]; s1 = s4[i1]; }
        PROC(d0, s0);
        if (have1) PROC(d1, s1);
    }
#undef PROC
    __syncthreads();
    unsigned* __restrict__ outp = partials + (size_t)blockIdx.x * TBIN;
    for (int j = tid; j < TBIN; j += 1024) outp[j] = acc[j];
}

template <int TBIN, int TNBINS>
__global__ void finalize_binned(const unsigned* __restrict__ partials,
                                const float* __restrict__ Ws,
                                float* __restrict__ out, int n, int nslices) {
    int i = blockIdx.x * blockDim.x + threadIdx.x;
    if (i >= n) return;
    const int bin = i / TBIN;
    const int local = i % TBIN;
    int cnt = 0, sum = 0;
    for (int s = 0; s < nslices; ++s) {
        unsigned p = partials[(size_t)(s * TNBINS + bin) * TBIN + local];
        cnt += (int)(p & 0xFFu);
        sum += ((int)p) >> 8;
    }
    float mean = ((float)sum * (1.0f / HSCALE)) / (float)max(cnt, 1);
    float2 o;
    o.x = mean * Ws[0];
    o.y = mean * Ws[1];
    ((float2*)out)[i] = o;
}

__global__ void scatter_atomic(const int* __restrict__ src,
                               const int* __restrict__ dst,
                               const int* __restrict__ hfix,
                               unsigned long long* __restrict__ packed) {
    int tid = blockIdx.x * blockDim.x + threadIdx.x;
    int stride = gridDim.x * blockDim.x;
    const int4* __restrict__ src4 = (const int4*)src;
    const int4* __restrict__ dst4 = (const int4*)dst;
    const int n4 = N_EDGES / 4;
    for (int e = tid; e < n4; e += stride) {
        int4 s = src4[e];
        int4 d = dst4[e];
        long long h0 = hfix[s.x], h1 = hfix[s.y], h2 = hfix[s.z], h3 = hfix[s.w];
        atomicAdd(&packed[d.x], ((unsigned long long)(h0 << 20)) + 1ull);
        atomicAdd(&packed[d.y], ((unsigned long long)(h1 << 20)) + 1ull);
        atomicAdd(&packed[d.z], ((unsigned long long)(h2 << 20)) + 1ull);
        atomicAdd(&packed[d.w], ((unsigned long long)(h3 << 20)) + 1ull);
    }
}

__global__ void finalize_atomic(const unsigned long long* __restrict__ packed,
                                const float* __restrict__ Ws,
                                float* __restrict__ out, int n) {
    int i = blockIdx.x * blockDim.x + threadIdx.x;
    if (i >= n) return;
    long long p = (long long)packed[i];
    int cnt = (int)(p & 0xFFFFFll);
    long long sf = p >> 20;
    float mean = ((float)sf * (1.0f / HSCALE)) / (float)max(cnt, 1);
    float2 o;
    o.x = mean * Ws[0];
    o.y = mean * Ws[1];
    ((float2*)out)[i] = o;
}

extern "C" void kernel_launch(void* const* d_in, const int* in_sizes, int n_in,
                              void* d_out, int out_size, void* d_ws, size_t ws_size,
                              hipStream_t stream) {
    const float* x  = (const float*)d_in[0];
    const float* W1 = (const float*)d_in[1];
    const float* b1 = (const float*)d_in[2];
    const float* W2 = (const float*)d_in[3];
    const float* b2 = (const float*)d_in[4];
    const float* Ws = (const float*)d_in[5];
    const int*   ei = (const int*)d_in[6];   // [2, N_EDGES] row-major
    const int* src = ei;
    const int* dst = ei + N_EDGES;
    float* out = (float*)d_out;

    const int blk = 256;
    const int nblk_nodes = (N_NODES + blk - 1) / blk;

    int* hfix = (int*)d_ws;                         // [N] @ 0 (512KB reserved)
    const size_t base = 512 * 1024;

    // --- Primary: fixed-segment partition + fused accumulate/finalize. ----
    const size_t counts_off = base;                                   // 20KB
    const size_t done_off   = base + 24 * 1024;                       // 100B
    const size_t recs_off   = base + 32 * 1024;
    const size_t recs_bytes = (size_t)NQBINS * PBLOCKS * LCAP * sizeof(unsigned);
    const size_t part_off   = recs_off + recs_bytes;
    const size_t part_bytes = (size_t)NQBINS * NQBLK * QBIN * sizeof(unsigned);
    const size_t need_part  = part_off + part_bytes;  // ~39.5 MiB

    if (ws_size >= need_part) {
        unsigned* counts   = (unsigned*)((char*)d_ws + counts_off);
        unsigned* done     = (unsigned*)((char*)d_ws + done_off);
        unsigned* recs     = (unsigned*)((char*)d_ws + recs_off);
        unsigned* partials = (unsigned*)((char*)d_ws + part_off);

        (void)hipFuncSetAttribute(
            reinterpret_cast<const void*>(&partition_kernel),
            hipFuncAttributeMaxDynamicSharedMemorySize,
            NQBINS * LCAP * (int)sizeof(unsigned));

        partition_kernel<<<PBLOCKS, PTHREADS,
                           NQBINS * LCAP * sizeof(unsigned), stream>>>(
            x, W1, b1, W2, b2, src, dst, hfix, recs, counts, done);
        accumulate_kernel<<<NQBINS * NQBLK, QTHREADS, 0, stream>>>(
            recs, counts, hfix, partials, done, Ws, out);
        return;
    }

    // --- Fallback 1: 3 bins x 33792 (132KB dynamic LDS), G slices. --------
    constexpr int BIN3 = 33792;
    constexpr int NB3 = 3;
    (void)hipFuncSetAttribute(
        reinterpret_cast<const void*>(&scatter_binned<BIN3, NB3>),
        hipFuncAttributeMaxDynamicSharedMemorySize, BIN3 * sizeof(unsigned));
    unsigned* partials = (unsigned*)((char*)d_ws + base);
    const int cands3[3] = {80, 64, 32};
    for (int c = 0; c < 3; ++c) {
        int G3 = cands3[c];
        if (ws_size < base + (size_t)G3 * NB3 * BIN3 * sizeof(unsigned)) continue;
        mlp_kernel<<<nblk_nodes, blk, 0, stream>>>(x, W1, b1, W2, b2, hfix,
                                                   N_NODES);
        int n4s = (N_EDGES / 4) / G3;
        scatter_binned<BIN3, NB3>
            <<<G3 * NB3, 1024, BIN3 * sizeof(unsigned), stream>>>(
                src, dst, hfix, partials, n4s);
        finalize_binned<BIN3, NB3><<<nblk_nodes, blk, 0, stream>>>(
            partials, Ws, out, N_NODES, G3);
        return;
    }

    // --- Fallback 2: packed u64 global atomics. ----------------------------
    mlp_kernel<<<nblk_nodes, blk, 0, stream>>>(x, W1, b1, W2, b2, hfix, N_NODES);
    unsigned long long* packed = (unsigned long long*)((char*)d_ws + base);
    hipMemsetAsync((void*)packed, 0, (size_t)N_NODES * sizeof(unsigned long long),
                   stream);
    scatter_atomic<<<2048, blk, 0, stream>>>(src, dst, hfix, packed);
    finalize_atomic<<<nblk_nodes, blk, 0, stream>>>(packed, Ws, out, N_NODES);
}

// Round 15
// 54.991 us; speedup vs baseline: 2.7093x; 2.7093x over previous
//
#include <hip/hip_runtime.h>

#define N_NODES 100000
#define N_EDGES 6400000

#define HSCALE 4096.0f           // 2^12 fixed point for h
#define HCLAMP 63.0f             // |hfix| <= 258048 < 2^18

// ---- Partition geometry (R13-validated structure; 200-block variant) -------
#define QBIN       4096          // nodes per bin (pow2 -> shift/mask)
#define QBIN_SHIFT 12
#define NQBINS     25            // 25*4096 = 102400 >= 100000
#define PBLOCKS    200           // 8000 quads per block, exact
#define PTHREADS   1024
#define LCAP       1536          // per-(bin,block) segment: mean 1280, +7.2 sigma
#define NQBLK      20            // accumulate blocks per bin -> grid 500
#define QTHREADS   1024

typedef int int4v __attribute__((ext_vector_type(4)));
typedef unsigned uint4v __attribute__((ext_vector_type(4)));

// ---------------------------------------------------------------------------
// Pass P (fused MLP + partition).  4-quad ILP; rec = (src<<12)|(dst&4095);
// per-bin LDS buckets -> fixed global segments (no global atomics, nothing
// zeroed between calls).  NOTE: no device-scope fences anywhere — kernel
// boundaries provide cross-XCD coherence for free (R14 lesson: an in-kernel
// __threadfence costs an L2 writeback per call site on non-coherent XCDs).
// ---------------------------------------------------------------------------
__global__ __launch_bounds__(PTHREADS)
void partition_kernel(const float* __restrict__ x,
                      const float* __restrict__ W1,
                      const float* __restrict__ b1,
                      const float* __restrict__ W2,
                      const float* __restrict__ b2,
                      const int* __restrict__ src,
                      const int* __restrict__ dst,
                      int* __restrict__ hfix,
                      unsigned* __restrict__ recs,     // [NQBINS*PBLOCKS*LCAP]
                      unsigned* __restrict__ counts) { // [NQBINS*PBLOCKS]
    extern __shared__ unsigned sbuf[];                 // NQBINS*LCAP u32 (150KB)
    __shared__ unsigned scnt[NQBINS];
    const int tid = threadIdx.x;

    // --- fused MLP: one node per thread across the grid (200*1024 > 100000
    // covers all nodes in the first 98 blocks' threads). ---
    int node = blockIdx.x * PTHREADS + tid;
    if (node < N_NODES) {
        float xv = x[node];
        float acc = b2[0];
#pragma unroll
        for (int k = 0; k < 16; ++k) {
            float t = fmaxf(W1[k] * xv + b1[k], 0.0f);
            acc = fmaf(W2[k], t, acc);
        }
        acc = fminf(fmaxf(acc, -HCLAMP), HCLAMP);
        hfix[node] = __float2int_rn(acc * HSCALE);
    }

    if (tid < NQBINS) scnt[tid] = 0u;
    __syncthreads();

    const int quads = (N_EDGES / 4) / PBLOCKS;          // 8000 exact
    const int4v* __restrict__ s4 = (const int4v*)src + (size_t)blockIdx.x * quads;
    const int4v* __restrict__ d4 = (const int4v*)dst + (size_t)blockIdx.x * quads;

#define PROC(D, S)                                                            \
    {                                                                         \
        int b0 = (D).x >> QBIN_SHIFT, b1_ = (D).y >> QBIN_SHIFT;              \
        int b2_ = (D).z >> QBIN_SHIFT, b3 = (D).w >> QBIN_SHIFT;              \
        unsigned r0 = ((unsigned)(S).x << 12) | (unsigned)((D).x & (QBIN-1)); \
        unsigned r1 = ((unsigned)(S).y << 12) | (unsigned)((D).y & (QBIN-1)); \
        unsigned r2 = ((unsigned)(S).z << 12) | (unsigned)((D).z & (QBIN-1)); \
        unsigned r3 = ((unsigned)(S).w << 12) | (unsigned)((D).w & (QBIN-1)); \
        unsigned sl0 = atomicAdd(&scnt[b0], 1u);                              \
        unsigned sl1 = atomicAdd(&scnt[b1_], 1u);                             \
        unsigned sl2 = atomicAdd(&scnt[b2_], 1u);                             \
        unsigned sl3 = atomicAdd(&scnt[b3], 1u);                              \
        if (sl0 < (unsigned)LCAP) sbuf[b0 * LCAP + sl0] = r0;                 \
        if (sl1 < (unsigned)LCAP) sbuf[b1_ * LCAP + sl1] = r1;                \
        if (sl2 < (unsigned)LCAP) sbuf[b2_ * LCAP + sl2] = r2;                \
        if (sl3 < (unsigned)LCAP) sbuf[b3 * LCAP + sl3] = r3;                 \
    }

    for (int i = tid; i < quads; i += 4 * PTHREADS) {
        const int i1 = i + PTHREADS, i2 = i + 2 * PTHREADS, i3 = i + 3 * PTHREADS;
        const bool h1 = i1 < quads, h2 = i2 < quads, h3 = i3 < quads;
        int4v d0 = d4[i];
        int4v s0 = s4[i];
        int4v d1, s1, d2, s2, d3, s3;
        if (h1) { d1 = d4[i1]; s1 = s4[i1]; }
        if (h2) { d2 = d4[i2]; s2 = s4[i2]; }
        if (h3) { d3 = d4[i3]; s3 = s4[i3]; }
        PROC(d0, s0);
        if (h1) PROC(d1, s1);
        if (h2) PROC(d2, s2);
        if (h3) PROC(d3, s3);
    }
#undef PROC
    __syncthreads();

    // Publish counts; flush buckets to fixed segments with uint4 stores.
    if (tid < NQBINS)
        counts[tid * PBLOCKS + blockIdx.x] = min(scnt[tid], (unsigned)LCAP);
    for (int b = 0; b < NQBINS; ++b) {
        const unsigned m = min(scnt[b], (unsigned)LCAP);
        const unsigned q = (m + 3u) >> 2;               // <= 384
        uint4v* __restrict__ segq =
            (uint4v*)(recs + ((size_t)b * PBLOCKS + blockIdx.x) * LCAP);
        const uint4v* __restrict__ sq = (const uint4v*)(sbuf + b * LCAP);
        for (unsigned t = tid; t < q; t += PTHREADS) segq[t] = sq[t];
    }
}

// ---------------------------------------------------------------------------
// Pass Q: per-bin accumulation.  4 thread-groups of 256 own strided segments;
// uint4 record loads -> 4 gather chains in flight -> 4 guarded LDS atomics.
// Garbage beyond count is masked (rec=0 -> gather hits hfix[0], discarded).
// ---------------------------------------------------------------------------
__global__ __launch_bounds__(QTHREADS)
void accumulate_kernel(const unsigned* __restrict__ recs,
                       const unsigned* __restrict__ counts,
                       const int* __restrict__ hfix,
                       unsigned* __restrict__ partials) {
    __shared__ unsigned acc[QBIN];   // 16 KB
    const int b = blockIdx.x / NQBLK;
    const int j = blockIdx.x % NQBLK;
    const int tid = threadIdx.x;
    const int grp = tid >> 8;        // 0..3
    const int slot = tid & 255;
    for (int k = tid; k < QBIN; k += QTHREADS) acc[k] = 0u;
    __syncthreads();

    const unsigned* __restrict__ cnts = counts + (size_t)b * PBLOCKS;
    const unsigned* __restrict__ bbase = recs + (size_t)b * PBLOCKS * LCAP;

    // Segments for this block: s = j + k*NQBLK, k = 0..PBLOCKS/NQBLK-1 (=10).
    for (int k = grp; k * NQBLK + j < PBLOCKS; k += 4) {
        const int s = j + k * NQBLK;
        const unsigned m = cnts[s];
        const unsigned q = (m + 3u) >> 2;               // uint4 count <= 384
        const uint4v* __restrict__ seg4 =
            (const uint4v*)(bbase + (size_t)s * LCAP);
        for (unsigned t = slot; t < q; t += 256) {
            uint4v v = seg4[t];
            const unsigned e0 = t * 4u;
            const bool g0 = e0 < m, g1 = e0 + 1 < m, g2 = e0 + 2 < m,
                       g3 = e0 + 3 < m;
            unsigned r0 = g0 ? v.x : 0u;
            unsigned r1 = g1 ? v.y : 0u;
            unsigned r2 = g2 ? v.z : 0u;
            unsigned r3 = g3 ? v.w : 0u;
            int f0 = hfix[r0 >> 12];
            int f1 = hfix[r1 >> 12];
            int f2 = hfix[r2 >> 12];
            int f3 = hfix[r3 >> 12];
            if (g0) atomicAdd(&acc[r0 & (QBIN - 1)], (((unsigned)f0) << 8) + 1u);
            if (g1) atomicAdd(&acc[r1 & (QBIN - 1)], (((unsigned)f1) << 8) + 1u);
            if (g2) atomicAdd(&acc[r2 & (QBIN - 1)], (((unsigned)f2) << 8) + 1u);
            if (g3) atomicAdd(&acc[r3 & (QBIN - 1)], (((unsigned)f3) << 8) + 1u);
        }
    }
    __syncthreads();

    unsigned* __restrict__ outp = partials + (size_t)blockIdx.x * QBIN;
    for (int k = tid; k < QBIN; k += QTHREADS) outp[k] = acc[k];
}

// ---------------------------------------------------------------------------
// Pass F: reduce NQBLK partials per node, decode, mean, apply Ws.  Separate
// dispatch: the kernel boundary is the (free) cross-XCD coherence point.
// ---------------------------------------------------------------------------
__global__ void finalize_part(const unsigned* __restrict__ partials,
                              const float* __restrict__ Ws,
                              float* __restrict__ out, int n) {
    int i = blockIdx.x * blockDim.x + threadIdx.x;
    if (i >= n) return;
    const int bin = i >> QBIN_SHIFT;
    const int local = i & (QBIN - 1);
    int cnt = 0, sum = 0;
#pragma unroll
    for (int j = 0; j < NQBLK; ++j) {
        unsigned p = partials[(size_t)(bin * NQBLK + j) * QBIN + local];
        cnt += (int)(p & 0xFFu);
        sum += ((int)p) >> 8;
    }
    float mean = ((float)sum * (1.0f / HSCALE)) / (float)max(cnt, 1);
    float2 o;
    o.x = mean * Ws[0];
    o.y = mean * Ws[1];
    ((float2*)out)[i] = o;
}

// ===========================================================================
// Fallback path kernels (small workspace): standalone MLP + LDS-binned
// 3-pass scatter (R5) + packed u64 global atomics (R2).
// ===========================================================================
__global__ void mlp_kernel(const float* __restrict__ x,
                           const float* __restrict__ W1,
                           const float* __restrict__ b1,
                           const float* __restrict__ W2,
                           const float* __restrict__ b2,
                           int* __restrict__ hfix, int n) {
    int i = blockIdx.x * blockDim.x + threadIdx.x;
    if (i >= n) return;
    float xv = x[i];
    float acc = b2[0];
#pragma unroll
    for (int k = 0; k < 16; ++k) {
        float t = fmaxf(W1[k] * xv + b1[k], 0.0f);
        acc = fmaf(W2[k], t, acc);
    }
    acc = fminf(fmaxf(acc, -HCLAMP), HCLAMP);
    hfix[i] = __float2int_rn(acc * HSCALE);
}

template <int TBIN, int TNBINS>
__global__ __launch_bounds__(1024)
void scatter_binned(const int* __restrict__ src,
                    const int* __restrict__ dst,
                    const int* __restrict__ hfix,
                    unsigned* __restrict__ partials,
                    int n4_per_slice) {
    extern __shared__ unsigned acc[];
    const int bin   = blockIdx.x % TNBINS;
    const int slice = blockIdx.x / TNBINS;
    const int tid = threadIdx.x;
    for (int j = tid; j < TBIN; j += 1024) acc[j] = 0u;
    __syncthreads();
    const int bin_lo = bin * TBIN;
    const int4* __restrict__ s4 = (const int4*)src + (size_t)slice * n4_per_slice;
    const int4* __restrict__ d4 = (const int4*)dst + (size_t)slice * n4_per_slice;
#define PROC(dd, ss)                                                          \
    {                                                                         \
        unsigned r;                                                           \
        r = (unsigned)((dd).x - bin_lo);                                      \
        if (r < (unsigned)TBIN)                                               \
            atomicAdd(&acc[r], (((unsigned)hfix[(ss).x]) << 8) + 1u);         \
        r = (unsigned)((dd).y - bin_lo);                                      \
        if (r < (unsigned)TBIN)                                               \
            atomicAdd(&acc[r], (((unsigned)hfix[(ss).y]) << 8) + 1u);         \
        r = (unsigned)((dd).z - bin_lo);                                      \
        if (r < (unsigned)TBIN)                                               \
            atomicAdd(&acc[r], (((unsigned)hfix[(ss).z]) << 8) + 1u);         \
        r = (unsigned)((dd).w - bin_lo);                                      \
        if (r < (unsigned)TBIN)                                               \
            atomicAdd(&acc[r], (((unsigned)hfix[(ss).w]) << 8) + 1u);         \
    }
    for (int i = tid; i < n4_per_slice; i += 2048) {
        int4 d0 = d4[i];
        int4 s0 = s4[i];
        const int i1 = i + 1024;
        int4 d1, s1;
        const bool have1 = i1 < n4_per_slice;
        if (have1) { d1 = d4[i1]; s1 = s4[i1]; }
        PROC(d0, s0);
        if (have1) PROC(d1, s1);
    }
#undef PROC
    __syncthreads();
    unsigned* __restrict__ outp = partials + (size_t)blockIdx.x * TBIN;
    for (int j = tid; j < TBIN; j += 1024) outp[j] = acc[j];
}

template <int TBIN, int TNBINS>
__global__ void finalize_binned(const unsigned* __restrict__ partials,
                                const float* __restrict__ Ws,
                                float* __restrict__ out, int n, int nslices) {
    int i = blockIdx.x * blockDim.x + threadIdx.x;
    if (i >= n) return;
    const int bin = i / TBIN;
    const int local = i % TBIN;
    int cnt = 0, sum = 0;
    for (int s = 0; s < nslices; ++s) {
        unsigned p = partials[(size_t)(s * TNBINS + bin) * TBIN + local];
        cnt += (int)(p & 0xFFu);
        sum += ((int)p) >> 8;
    }
    float mean = ((float)sum * (1.0f / HSCALE)) / (float)max(cnt, 1);
    float2 o;
    o.x = mean * Ws[0];
    o.y = mean * Ws[1];
    ((float2*)out)[i] = o;
}

__global__ void scatter_atomic(const int* __restrict__ src,
                               const int* __restrict__ dst,
                               const int* __restrict__ hfix,
                               unsigned long long* __restrict__ packed) {
    int tid = blockIdx.x * blockDim.x + threadIdx.x;
    int stride = gridDim.x * blockDim.x;
    const int4* __restrict__ src4 = (const int4*)src;
    const int4* __restrict__ dst4 = (const int4*)dst;
    const int n4 = N_EDGES / 4;
    for (int e = tid; e < n4; e += stride) {
        int4 s = src4[e];
        int4 d = dst4[e];
        long long h0 = hfix[s.x], h1 = hfix[s.y], h2 = hfix[s.z], h3 = hfix[s.w];
        atomicAdd(&packed[d.x], ((unsigned long long)(h0 << 20)) + 1ull);
        atomicAdd(&packed[d.y], ((unsigned long long)(h1 << 20)) + 1ull);
        atomicAdd(&packed[d.z], ((unsigned long long)(h2 << 20)) + 1ull);
        atomicAdd(&packed[d.w], ((unsigned long long)(h3 << 20)) + 1ull);
    }
}

__global__ void finalize_atomic(const unsigned long long* __restrict__ packed,
                                const float* __restrict__ Ws,
                                float* __restrict__ out, int n) {
    int i = blockIdx.x * blockDim.x + threadIdx.x;
    if (i >= n) return;
    long long p = (long long)packed[i];
    int cnt = (int)(p & 0xFFFFFll);
    long long sf = p >> 20;
    float mean = ((float)sf * (1.0f / HSCALE)) / (float)max(cnt, 1);
    float2 o;
    o.x = mean * Ws[0];
    o.y = mean * Ws[1];
    ((float2*)out)[i] = o;
}

extern "C" void kernel_launch(void* const* d_in, const int* in_sizes, int n_in,
                              void* d_out, int out_size, void* d_ws, size_t ws_size,
                              hipStream_t stream) {
    const float* x  = (const float*)d_in[0];
    const float* W1 = (const float*)d_in[1];
    const float* b1 = (const float*)d_in[2];
    const float* W2 = (const float*)d_in[3];
    const float* b2 = (const float*)d_in[4];
    const float* Ws = (const float*)d_in[5];
    const int*   ei = (const int*)d_in[6];   // [2, N_EDGES] row-major
    const int* src = ei;
    const int* dst = ei + N_EDGES;
    float* out = (float*)d_out;

    const int blk = 256;
    const int nblk_nodes = (N_NODES + blk - 1) / blk;

    int* hfix = (int*)d_ws;                         // [N] @ 0 (512KB reserved)
    const size_t base = 512 * 1024;

    // --- Primary: fixed-segment partition + accumulate + finalize. --------
    const size_t counts_off = base;                                   // 20KB
    const size_t recs_off   = base + 32 * 1024;
    const size_t recs_bytes = (size_t)NQBINS * PBLOCKS * LCAP * sizeof(unsigned);
    const size_t part_off   = recs_off + recs_bytes;
    const size_t part_bytes = (size_t)NQBINS * NQBLK * QBIN * sizeof(unsigned);
    const size_t need_part  = part_off + part_bytes;  // ~37.6 MiB

    if (ws_size >= need_part) {
        unsigned* counts   = (unsigned*)((char*)d_ws + counts_off);
        unsigned* recs     = (unsigned*)((char*)d_ws + recs_off);
        unsigned* partials = (unsigned*)((char*)d_ws + part_off);

        (void)hipFuncSetAttribute(
            reinterpret_cast<const void*>(&partition_kernel),
            hipFuncAttributeMaxDynamicSharedMemorySize,
            NQBINS * LCAP * (int)sizeof(unsigned));

        partition_kernel<<<PBLOCKS, PTHREADS,
                           NQBINS * LCAP * sizeof(unsigned), stream>>>(
            x, W1, b1, W2, b2, src, dst, hfix, recs, counts);
        accumulate_kernel<<<NQBINS * NQBLK, QTHREADS, 0, stream>>>(
            recs, counts, hfix, partials);
        finalize_part<<<nblk_nodes, blk, 0, stream>>>(partials, Ws, out, N_NODES);
        return;
    }

    // --- Fallback 1: 3 bins x 33792 (132KB dynamic LDS), G slices. --------
    constexpr int BIN3 = 33792;
    constexpr int NB3 = 3;
    (void)hipFuncSetAttribute(
        reinterpret_cast<const void*>(&scatter_binned<BIN3, NB3>),
        hipFuncAttributeMaxDynamicSharedMemorySize, BIN3 * sizeof(unsigned));
    unsigned* partials = (unsigned*)((char*)d_ws + base);
    const int cands3[3] = {80, 64, 32};
    for (int c = 0; c < 3; ++c) {
        int G3 = cands3[c];
        if (ws_size < base + (size_t)G3 * NB3 * BIN3 * sizeof(unsigned)) continue;
        mlp_kernel<<<nblk_nodes, blk, 0, stream>>>(x, W1, b1, W2, b2, hfix,
                                                   N_NODES);
        int n4s = (N_EDGES / 4) / G3;
        scatter_binned<BIN3, NB3>
            <<<G3 * NB3, 1024, BIN3 * sizeof(unsigned), stream>>>(
                src, dst, hfix, partials, n4s);
        finalize_binned<BIN3, NB3><<<nblk_nodes, blk, 0, stream>>>(
            partials, Ws, out, N_NODES, G3);
        return;
    }

    // --- Fallback 2: packed u64 global atomics. ----------------------------
    mlp_kernel<<<nblk_nodes, blk, 0, stream>>>(x, W1, b1, W2, b2, hfix, N_NODES);
    unsigned long long* packed = (unsigned long long*)((char*)d_ws + base);
    hipMemsetAsync((void*)packed, 0, (size_t)N_NODES * sizeof(unsigned long long),
                   stream);
    scatter_atomic<<<2048, blk, 0, stream>>>(src, dst, hfix, packed);
    finalize_atomic<<<nblk_nodes, blk, 0, stream>>>(packed, Ws, out, N_NODES);
}